// Round 1
// 148.073 us; speedup vs baseline: 1.0141x; 1.0141x over previous
//
#include <hip/hip_runtime.h>
#include <math.h>

// Problem constants: feat (B=16, C=4, h=128, w=240), MAX_DISP=24,
// output (B,1,1024,1920) fp32.
#define BB 16
#define CC 4
#define HH 128
#define WW 240
#define MAXD 24
#define OH 1024
#define OW 1920

// Fused: cost volume + softmax-expectation + x8 + bilinear align-corners resize.
// One block per (b, y0). Restructure vs previous version:
//  - sR channel-interleaved (float4 per x): phase 2 does ONE ds_read_b128 per
//    (pixel, d) instead of 4 ds_read_b32 -> 4x fewer LDS instrs, ~2x LDS cycles,
//    lane stride 16B = conflict-free b128 pattern.
//  - softmax un-stabilized: cost >= 0 so exp(-cost) in (0,1]; no overflow, and
//    worst-case ~e^-50 is far above fp32 denormal floor. Removes the cost[24]
//    VGPR array + min pass.
//  - x-interp hoisted into registers (ax/bx per ox-quad, loop-invariant across
//    rows): phase-3 vx LDS buffer, its barrier, and all phase-4 LDS reads gone.
//  - 512 threads, 1 pixel/thread; __launch_bounds__(512,8) pins VGPR<=64 so
//    32 waves/CU co-reside (LDS 10.3 KB, not limiting).
__global__ __launch_bounds__(512, 8) void fused_kernel(const float* __restrict__ fl,
                                                       const float* __restrict__ fr,
                                                       float* __restrict__ out) {
    const int blk = blockIdx.x;           // b*HH + y0
    const int b = blk >> 7;
    const int y0 = blk & (HH - 1);
    const int y1 = min(y0 + 1, HH - 1);
    const int tid = threadIdx.x;

    __shared__ float4 sR[2][WW + MAXD - 1];   // channel-interleaved, left-pad 23
    __shared__ float sP[2][WW];               // pred rows (already x8 scaled)

    // Per-thread pixel identity (480 of 512 threads active in compute phases).
    const bool act = tid < 2 * WW;
    const int pr = (tid < WW) ? 0 : 1;
    const int px = (tid < WW) ? tid : tid - WW;
    const int prow = pr ? y1 : y0;

    // Left features for this thread's pixel -- issue before LDS staging so the
    // global-load latency overlaps it.
    float4 l4 = make_float4(0.f, 0.f, 0.f, 0.f);
    if (act) {
        const size_t g = (((size_t)b * CC) * HH + prow) * WW + px;
        l4.x = fl[g];
        l4.y = fl[g + (size_t)HH * WW];
        l4.z = fl[g + (size_t)2 * HH * WW];
        l4.w = fl[g + (size_t)3 * HH * WW];
    }

    // Phase 1: stage right rows channel-interleaved. Consecutive tid ->
    // consecutive LDS dword (conflict-free); global reads are 4x 64B segments
    // per wave-instr (c = i&3 plane-strided, x = i>>2 contiguous).
    for (int i = tid; i < 2 * CC * WW; i += 512) {
        const int r = (i < CC * WW) ? 0 : 1;
        const int rem = (i < CC * WW) ? i : i - CC * WW;
        const int x = rem >> 2;
        const int c = rem & 3;
        const int row = r ? y1 : y0;
        ((float*)&sR[r][MAXD - 1 + x])[c] =
            fr[(((size_t)b * CC + c) * HH + row) * WW + x];
    }
    if (tid < 2 * CC * (MAXD - 1)) {          // zero left pad (184 dwords)
        const int r = (tid < CC * (MAXD - 1)) ? 0 : 1;
        const int rem = (tid < CC * (MAXD - 1)) ? tid : tid - CC * (MAXD - 1);
        ((float*)&sR[r][0])[rem] = 0.0f;
    }
    __syncthreads();

    // Phase 2: cost volume + softmax expectation (un-stabilized), x8.
    if (act) {
        float s = 0.0f, ws = 0.0f;
#pragma unroll
        for (int d = 0; d < MAXD; ++d) {
            const float4 r4 = sR[pr][MAXD - 1 + px - d];   // one b128, offset imm
            const float cv = fabsf(l4.x - r4.x) + fabsf(l4.y - r4.y)
                           + fabsf(l4.z - r4.z) + fabsf(l4.w - r4.w);
            const float p = __expf(-cv);                   // softmax(-cost)
            s += p;
            ws += p * (float)d;
        }
        sP[pr][px] = 8.0f * (ws / s);          // * img_h / h = 1024/128
    }
    __syncthreads();

    // Phase 3: x-interp hoisted to registers. Thread t owns output columns
    // 4t..4t+3 for EVERY row this block writes, so the sP taps and x-interp
    // are row-invariant: 16 LDS reads total, then pure-register row loop.
    const float sxf = (float)(WW - 1) / (float)(OW - 1);   // 239/1919
    float ax[4], bx[4];
    if (act) {                                  // 480 threads cover 1920/4
#pragma unroll
        for (int j = 0; j < 4; ++j) {
            const int ox = tid * 4 + j;
            const float xsf = (float)ox * sxf;
            int x0 = (int)xsf;
            if (x0 > WW - 1) x0 = WW - 1;
            const int x1 = min(x0 + 1, WW - 1);
            const float wx = xsf - (float)x0;
            const float p0 = sP[0][x0], q0 = sP[0][x1];
            const float p1 = sP[1][x0], q1 = sP[1][x1];
            ax[j] = p0 + (q0 - p0) * wx;        // x-interp of pred row y0
            bx[j] = p1 + (q1 - p1) * wx;        // x-interp of pred row y1
        }
    }

    // Phase 4: y-interp + coalesced float4 stores for the ~8 oy rows owned by
    // this block (floor(oy*sy) == y0; each oy claimed by exactly one block).
    const float syf = (float)(HH - 1) / (float)(OH - 1);   // 127/1023
    const int base = (int)((float)y0 * ((float)(OH - 1) / (float)(HH - 1))) - 2;
    for (int k = 0; k < 13; ++k) {
        const int oy = base + k;
        if (oy < 0 || oy >= OH) continue;                  // block-uniform
        const float ysf = (float)oy * syf;
        int yy = (int)ysf;
        if (yy > HH - 1) yy = HH - 1;
        if (yy != y0) continue;                            // block-uniform
        const float wy = ysf - (float)yy;
        if (act) {
            float4 o;
            o.x = ax[0] + (bx[0] - ax[0]) * wy;
            o.y = ax[1] + (bx[1] - ax[1]) * wy;
            o.z = ax[2] + (bx[2] - ax[2]) * wy;
            o.w = ax[3] + (bx[3] - ax[3]) * wy;
            ((float4*)(out + ((size_t)b * OH + oy) * OW))[tid] = o;
        }
    }
}

extern "C" void kernel_launch(void* const* d_in, const int* in_sizes, int n_in,
                              void* d_out, int out_size, void* d_ws, size_t ws_size,
                              hipStream_t stream) {
    const float* feat_l = (const float*)d_in[0];
    const float* feat_r = (const float*)d_in[1];
    float* out = (float*)d_out;
    fused_kernel<<<BB * HH, 512, 0, stream>>>(feat_l, feat_r, out);
}